// Round 9
// baseline (5344.043 us; speedup 1.0000x reference)
//
#include <hip/hip_runtime.h>
#include <hip/hip_bf16.h>

typedef __hip_bfloat16 bf16;
typedef __attribute__((ext_vector_type(8))) short short8;
typedef __attribute__((ext_vector_type(4))) float float4v;
typedef __attribute__((ext_vector_type(2))) float float2v;

#define BATCH 8
#define SEQ   1568            // 49 segments x 32
#define M_TOK (BATCH*SEQ)     // 12544
#define DM    768
#define DI    1536
#define NXZ   3072
#define DS    16
#define DTR   48
#define NCLS  1000
#define LAYERS 4
#define NSEG  49
#define SEGL  32
#define NIN   21

__device__ __forceinline__ float b2f(bf16 v){ return __bfloat162float(v); }
__device__ __forceinline__ bf16  f2b(float v){ return __float2bfloat16(v); }
__device__ __forceinline__ float us2f(unsigned short u){
    unsigned v = ((unsigned)u) << 16; float f; __builtin_memcpy(&f, &v, 4); return f;
}

// ---------------------------------------------------------------- fused canonicalization
struct CanonDesc {
    const void* src[NIN];
    void*       dst[NIN];
    int         cum[NIN+1];   // cumulative element offsets
    unsigned    isf32;        // bit i: dst i is fp32
};

__global__ __launch_bounds__(256)
void canon_all(CanonDesc cd, const unsigned short* __restrict__ probe)
{
    bool f32in = (probe[0] == 0);          // norm_w[0]==1.0: fp32 low half = 0
    int i = blockIdx.x*256 + threadIdx.x;
    if (i >= cd.cum[NIN]) return;
    int lo = 0, hi = NIN;
    while (hi - lo > 1) { int mid = (lo+hi) >> 1; if (i >= cd.cum[mid]) lo = mid; else hi = mid; }
    int e = i - cd.cum[lo];
    float v = f32in ? ((const float*)cd.src[lo])[e] : b2f(((const bf16*)cd.src[lo])[e]);
    if ((cd.isf32 >> lo) & 1) ((float*)cd.dst[lo])[e] = v;
    else                      ((bf16*) cd.dst[lo])[e] = f2b(v);
}

// ---------------------------------------------------------------- gather patches (per batch-group)
__global__ __launch_bounds__(256)
void gather_patches(const bf16* __restrict__ x, bf16* __restrict__ Ap, int b0)
{
    size_t idx = (size_t)blockIdx.x*256 + threadIdx.x;
    int i = (int)(idx & 255);
    int m = (int)(idx >> 8);
    int b = b0 + m / SEQ, s = m % SEQ;
    int hw = s >> 3, c = s & 7;
    int h = hw / 14, w = hw % 14;
    int p = i >> 4, q = i & 15;
    Ap[idx] = x[(((size_t)(b*8 + c)*224) + h*16 + p)*224 + w*16 + q];
}

// ---------------------------------------------------------------- MFMA GEMM (128x128, BK=32)
// epi 0: Cb=bf16(acc); epi 2: Cf+=acc; epi 3: Cf=acc+bias[n]+chan[(m&7)*N+n]
__global__ __launch_bounds__(256)
void gemm_mfma(const bf16* __restrict__ A, int lda,
               const bf16* __restrict__ W, int ldw,
               float* __restrict__ Cf, bf16* __restrict__ Cb, int ldc,
               const float* __restrict__ bias, const float* __restrict__ chan,
               int M, int N, int K, int epi)
{
    __shared__ short As[128*40];
    __shared__ short Bs[128*40];
    int tid  = threadIdx.x;
    int m0   = blockIdx.x*128, n0 = blockIdx.y*128;
    int lane = tid & 63, wv = tid >> 6;
    int wm = (wv >> 1)*64, wn = (wv & 1)*64;
    int l15 = lane & 15, quad = lane >> 4;

    float4v acc[4][4];
    #pragma unroll
    for (int i = 0; i < 4; ++i)
        #pragma unroll
        for (int j = 0; j < 4; ++j) acc[i][j] = (float4v){0.f,0.f,0.f,0.f};

    const short8 zv8 = {0,0,0,0,0,0,0,0};
    for (int k0 = 0; k0 < K; k0 += 32) {
        #pragma unroll
        for (int u = 0; u < 2; ++u) {
            int c   = tid*2 + u;
            int row = c >> 2, ch = c & 3;
            bool kok = (k0 + ch*8 + 8) <= K;
            short8 va = (kok && m0 + row < M)
                ? *(const short8*)((const short*)A + (size_t)(m0+row)*lda + k0 + ch*8) : zv8;
            *(short8*)(As + row*40 + ch*8) = va;
            short8 vb = (kok && n0 + row < N)
                ? *(const short8*)((const short*)W + (size_t)(n0+row)*ldw + k0 + ch*8) : zv8;
            *(short8*)(Bs + row*40 + ch*8) = vb;
        }
        __syncthreads();
        short8 av[4], bv[4];
        #pragma unroll
        for (int i = 0; i < 4; ++i) av[i] = *(const short8*)(As + (wm + i*16 + l15)*40 + quad*8);
        #pragma unroll
        for (int j = 0; j < 4; ++j) bv[j] = *(const short8*)(Bs + (wn + j*16 + l15)*40 + quad*8);
        #pragma unroll
        for (int i = 0; i < 4; ++i)
            #pragma unroll
            for (int j = 0; j < 4; ++j)
                acc[i][j] = __builtin_amdgcn_mfma_f32_16x16x32_bf16(av[i], bv[j], acc[i][j], 0, 0, 0);
        __syncthreads();
    }

    #pragma unroll
    for (int i = 0; i < 4; ++i) {
        #pragma unroll
        for (int j = 0; j < 4; ++j) {
            int gn = n0 + wn + j*16 + l15;
            if (gn >= N) continue;
            #pragma unroll
            for (int r = 0; r < 4; ++r) {
                int gm = m0 + wm + i*16 + quad*4 + r;
                if (gm >= M) continue;
                float v = acc[i][j][r];
                size_t off = (size_t)gm*ldc + gn;
                if (epi == 0)      Cb[off] = f2b(v);
                else if (epi == 2) Cf[off] += v;
                else               Cf[off] = v + bias[gn] + chan[(size_t)(gm & 7)*N + gn];
            }
        }
    }
}

// ---------------------------------------------------------------- LayerNorm 768 (fp32 in, bf16 out)
__global__ __launch_bounds__(256)
void ln768(const float* __restrict__ X, const float* __restrict__ w,
           const float* __restrict__ bb, bf16* __restrict__ out)
{
    __shared__ float red[8];
    size_t t = blockIdx.x;
    const float* x = X + t*DM;
    float v[3]; float s = 0.f, s2 = 0.f;
    #pragma unroll
    for (int r = 0; r < 3; ++r) {
        v[r] = x[threadIdx.x + 256*r];
        s += v[r]; s2 += v[r]*v[r];
    }
    #pragma unroll
    for (int o = 32; o; o >>= 1) { s += __shfl_down(s, o, 64); s2 += __shfl_down(s2, o, 64); }
    if ((threadIdx.x & 63) == 0) { red[threadIdx.x >> 6] = s; red[(threadIdx.x >> 6) + 4] = s2; }
    __syncthreads();
    s  = red[0]+red[1]+red[2]+red[3];
    s2 = red[4]+red[5]+red[6]+red[7];
    float mu  = s * (1.f/DM);
    float inv = rsqrtf(fmaxf(s2*(1.f/DM) - mu*mu, 0.f) + 1e-5f);
    #pragma unroll
    for (int r = 0; r < 3; ++r) {
        int i = threadIdx.x + 256*r;
        out[t*DM + i] = f2b((v[r]-mu)*inv*w[i] + bb[i]);
    }
}

// ---------------------------------------------------------------- causal depthwise conv (k=4) + silu
// reads x-half of xz (stride NXZ), writes xc (stride DI)
__global__ __launch_bounds__(256)
void conv_silu(const bf16* __restrict__ xz, const float* __restrict__ cw,
               const float* __restrict__ cb, bf16* __restrict__ xc)
{
    size_t idx = (size_t)blockIdx.x*256 + threadIdx.x;
    int d = (int)(idx % DI);
    int m = (int)(idx / DI);
    int b = m / SEQ, t = m % SEQ;
    float acc = cb[d];
    #pragma unroll
    for (int k = 0; k < 4; ++k) {
        int tt = t + k - 3;
        if (tt >= 0)
            acc += b2f(xz[(size_t)(b*SEQ + tt)*NXZ + d]) * cw[d*4 + k];
    }
    float sig = 1.f/(1.f + __expf(-acc));
    xc[idx] = f2b(acc*sig);
}

// ================================================================ chunked scan w/ fused dt_proj
// dt[m,d] = softplus(dbc[m,:48]·dtw[d,:] + bias[d]) computed in-kernel.
// 128-thread blocks: 16 d-chains x 8 state-pairs; grid = g*(DI/16)*NSEG.
#define DSTR 84   // dbcsh row stride (floats): 16B-aligned rows

__global__ __launch_bounds__(128)
void scan_p1f(const bf16* __restrict__ xc, const bf16* __restrict__ dbc,
              const bf16* __restrict__ dtw, const float* __restrict__ dtbias,
              const float* __restrict__ Alog,
              float* __restrict__ seg, float* __restrict__ sumdt)
{
    __shared__ float dbcsh[32][DSTR];   // [t][0:80]
    __shared__ float dtwsh[16][52];     // [dl][r]
    __shared__ float dtT[16][36], xT[16][36];

    int si = blockIdx.x % NSEG;
    int tt = blockIdx.x / NSEG;
    int dblk = tt % (DI/16);
    int b = tt / (DI/16);
    int d0 = dblk*16;
    int tid = threadIdx.x;
    int s  = tid & 7;        // states s*2, s*2+1
    int dl = tid >> 3;
    int d  = d0 + dl;
    size_t row0 = (size_t)(b*SEQ + si*SEGL);

    for (int c = tid; c < 320; c += 128) {           // dbc 32x80
        int r = c / 10, o = c % 10;
        short8 v = *(const short8*)((const unsigned short*)dbc + (row0 + r)*80 + o*8);
        #pragma unroll
        for (int i = 0; i < 8; ++i) dbcsh[r][o*8+i] = us2f((unsigned short)v[i]);
    }
    if (tid < 64) {                                   // xc 32x16 -> xT transposed
        int r = tid >> 1, hf = tid & 1;
        short8 v = *(const short8*)((const unsigned short*)xc + (row0 + r)*DI + d0 + hf*8);
        #pragma unroll
        for (int i = 0; i < 8; ++i) xT[hf*8+i][r] = us2f((unsigned short)v[i]);
    }
    if (tid < 96) {                                   // dtw 16x48
        int r = tid / 6, o = tid % 6;
        short8 v = *(const short8*)((const unsigned short*)dtw + (size_t)(d0 + r)*DTR + o*8);
        #pragma unroll
        for (int i = 0; i < 8; ++i) dtwsh[r][o*8+i] = us2f((unsigned short)v[i]);
    }
    __syncthreads();

    {   // dt -> dtT[dl][t]; each lane: 4 t for its dl-row
        int cdl = tid >> 3, o = tid & 7;
        float bias = dtbias[d0 + cdl];
        float4v accq = {bias, bias, bias, bias};
        #pragma unroll
        for (int r4 = 0; r4 < 12; ++r4) {
            float4v wv = *(const float4v*)&dtwsh[cdl][r4*4];
            #pragma unroll
            for (int q = 0; q < 4; ++q) {
                float4v bv = *(const float4v*)&dbcsh[o*4 + q][r4*4];
                accq[q] += wv[0]*bv[0] + wv[1]*bv[1] + wv[2]*bv[2] + wv[3]*bv[3];
            }
        }
        #pragma unroll
        for (int q = 0; q < 4; ++q) {
            float v = accq[q];
            accq[q] = (v > 20.f) ? v : log1pf(__expf(v));
        }
        *(float4v*)&dtT[cdl][o*4] = accq;
    }
    __syncthreads();

    float A2a = -__expf(Alog[(size_t)d*DS + s*2    ]) * 1.44269504f;
    float A2b = -__expf(Alog[(size_t)d*DS + s*2 + 1]) * 1.44269504f;
    float h0 = 0.f, h1 = 0.f, sdt = 0.f;
    #pragma unroll
    for (int jj = 0; jj < 8; ++jj) {
        float4v dv = *(const float4v*)&dtT[dl][jj*4];
        float4v xv = *(const float4v*)&xT [dl][jj*4];
        #pragma unroll
        for (int q = 0; q < 4; ++q) {
            int j = jj*4 + q;
            float dtv = dv[q], dtx = dtv*xv[q];
            sdt += dtv;
            float2v Bv = *(const float2v*)&dbcsh[j][DTR + s*2];
            h0 = exp2f(dtv*A2a)*h0 + dtx*Bv[0];
            h1 = exp2f(dtv*A2b)*h1 + dtx*Bv[1];
        }
    }
    size_t o = ((size_t)(b*NSEG + si)*DI + d)*DS + s*2;
    *(float2v*)&seg[o] = (float2v){h0, h1};
    if (s == 0) sumdt[(size_t)(b*NSEG + si)*DI + d] = sdt;
}

// ---- pass 2: 49-step boundary scan, in-place ----
__global__ __launch_bounds__(256)
void scan_p2(const float* __restrict__ Alog, const float* __restrict__ sumdt,
             float* seg)
{
    int dblk = blockIdx.x % (DI/16), b = blockIdx.x / (DI/16);
    int n = threadIdx.x & 15, dl = threadIdx.x >> 4;
    int d = dblk*16 + dl;
    float A2 = -__expf(Alog[(size_t)d*DS + n]) * 1.44269504f;
    float h = 0.f;
    for (int si = 0; si < NSEG; ++si) {
        float sdt = sumdt[(size_t)(b*NSEG + si)*DI + d];
        size_t o = ((size_t)(b*NSEG + si)*DI + d)*DS + n;
        float Bv = seg[o];
        seg[o] = h;
        h = exp2f(A2*sdt)*h + Bv;
    }
}

// ---- pass 3: within-segment scan from h_pre, fused dt, emit y ----
__global__ __launch_bounds__(128)
void scan_p3f(const bf16* __restrict__ xc, const bf16* __restrict__ dbc,
              const bf16* __restrict__ dtw, const float* __restrict__ dtbias,
              const float* __restrict__ Alog, const float* __restrict__ Dpar,
              const float* __restrict__ seg, bf16* __restrict__ y)
{
    __shared__ float dbcsh[32][DSTR];
    __shared__ float dtwsh[16][52];
    __shared__ float dtT[16][36], xT[16][36];
    __shared__ bf16  ys[32][16];

    int si = blockIdx.x % NSEG;
    int tt = blockIdx.x / NSEG;
    int dblk = tt % (DI/16);
    int b = tt / (DI/16);
    int d0 = dblk*16;
    int tid = threadIdx.x;
    int s  = tid & 7;
    int dl = tid >> 3;
    int d  = d0 + dl;
    size_t row0 = (size_t)(b*SEQ + si*SEGL);

    for (int c = tid; c < 320; c += 128) {
        int r = c / 10, o = c % 10;
        short8 v = *(const short8*)((const unsigned short*)dbc + (row0 + r)*80 + o*8);
        #pragma unroll
        for (int i = 0; i < 8; ++i) dbcsh[r][o*8+i] = us2f((unsigned short)v[i]);
    }
    if (tid < 64) {
        int r = tid >> 1, hf = tid & 1;
        short8 v = *(const short8*)((const unsigned short*)xc + (row0 + r)*DI + d0 + hf*8);
        #pragma unroll
        for (int i = 0; i < 8; ++i) xT[hf*8+i][r] = us2f((unsigned short)v[i]);
    }
    if (tid < 96) {
        int r = tid / 6, o = tid % 6;
        short8 v = *(const short8*)((const unsigned short*)dtw + (size_t)(d0 + r)*DTR + o*8);
        #pragma unroll
        for (int i = 0; i < 8; ++i) dtwsh[r][o*8+i] = us2f((unsigned short)v[i]);
    }
    __syncthreads();

    {
        int cdl = tid >> 3, o = tid & 7;
        float bias = dtbias[d0 + cdl];
        float4v accq = {bias, bias, bias, bias};
        #pragma unroll
        for (int r4 = 0; r4 < 12; ++r4) {
            float4v wv = *(const float4v*)&dtwsh[cdl][r4*4];
            #pragma unroll
            for (int q = 0; q < 4; ++q) {
                float4v bv = *(const float4v*)&dbcsh[o*4 + q][r4*4];
                accq[q] += wv[0]*bv[0] + wv[1]*bv[1] + wv[2]*bv[2] + wv[3]*bv[3];
            }
        }
        #pragma unroll
        for (int q = 0; q < 4; ++q) {
            float v = accq[q];
            accq[q] = (v > 20.f) ? v : log1pf(__expf(v));
        }
        *(float4v*)&dtT[cdl][o*4] = accq;
    }
    __syncthreads();

    float A2a = -__expf(Alog[(size_t)d*DS + s*2    ]) * 1.44269504f;
    float A2b = -__expf(Alog[(size_t)d*DS + s*2 + 1]) * 1.44269504f;
    float2v hv = *(const float2v*)&seg[((size_t)(b*NSEG + si)*DI + d)*DS + s*2];
    float h0 = hv[0], h1 = hv[1];
    float Dv = Dpar[d];

    float pr[32];
    #pragma unroll
    for (int jj = 0; jj < 8; ++jj) {
        float4v dv = *(const float4v*)&dtT[dl][jj*4];
        float4v xv = *(const float4v*)&xT [dl][jj*4];
        #pragma unroll
        for (int q = 0; q < 4; ++q) {
            int j = jj*4 + q;
            float dtv = dv[q], dtx = dtv*xv[q];
            float2v Bv = *(const float2v*)&dbcsh[j][DTR + s*2];
            float2v Cv = *(const float2v*)&dbcsh[j][DTR + DS + s*2];
            h0 = exp2f(dtv*A2a)*h0 + dtx*Bv[0];
            h1 = exp2f(dtv*A2b)*h1 + dtx*Bv[1];
            float p = h0*Cv[0] + h1*Cv[1];
            if (s == 0) p += Dv*xv[q];
            pr[j] = p;
        }
    }
    #pragma unroll
    for (int j = 0; j < 32; ++j) {
        float p = pr[j];
        p += __shfl_xor(p, 1, 8);
        p += __shfl_xor(p, 2, 8);
        p += __shfl_xor(p, 4, 8);
        if (s == 0) ys[j][dl] = f2b(p);
    }
    __syncthreads();
    if (tid < 64) {
        int r = tid >> 1, hf = tid & 1;
        short8 vy = *(const short8*)((const unsigned short*)&ys[r][0] + hf*8);
        *(short8*)((unsigned short*)y + (row0 + r)*DI + d0 + hf*8) = vy;
    }
}

// ---------------------------------------------------------------- LN(1536)*silu(z); in-place over y
__global__ __launch_bounds__(256)
void gate_ln(bf16* y, const bf16* __restrict__ xz,
             const float* __restrict__ w, const float* __restrict__ bb)
{
    __shared__ float red[8];
    size_t t = blockIdx.x;
    bf16* yy = y + t*DI;
    const bf16* zz = xz + t*NXZ + DI;
    float v[6]; float s = 0.f, s2 = 0.f;
    #pragma unroll
    for (int r = 0; r < 6; ++r) {
        v[r] = b2f(yy[threadIdx.x + 256*r]);
        s += v[r]; s2 += v[r]*v[r];
    }
    #pragma unroll
    for (int o = 32; o; o >>= 1) { s += __shfl_down(s, o, 64); s2 += __shfl_down(s2, o, 64); }
    if ((threadIdx.x & 63) == 0) { red[threadIdx.x >> 6] = s; red[(threadIdx.x >> 6) + 4] = s2; }
    __syncthreads();
    s  = red[0]+red[1]+red[2]+red[3];
    s2 = red[4]+red[5]+red[6]+red[7];
    float mu  = s * (1.f/DI);
    float inv = rsqrtf(fmaxf(s2*(1.f/DI) - mu*mu, 0.f) + 1e-5f);
    #pragma unroll
    for (int r = 0; r < 6; ++r) {
        int i = threadIdx.x + 256*r;
        float zv = b2f(zz[i]);
        float sig = 1.f/(1.f + __expf(-zv));
        yy[i] = f2b(((v[r]-mu)*inv*w[i] + bb[i]) * (zv*sig));
    }
}

// ---------------------------------------------------------------- mean pool over tokens
__global__ __launch_bounds__(256)
void pool_kernel(const bf16* __restrict__ hf, float* __restrict__ pooled)
{
    int idx = blockIdx.x*256 + threadIdx.x;
    int b = idx / DM, dm = idx % DM;
    const bf16* p = hf + (size_t)b*SEQ*DM + dm;
    float s = 0.f;
    for (int t = 0; t < SEQ; ++t) s += b2f(p[(size_t)t*DM]);
    pooled[idx] = s * (1.f/SEQ);
}

// ---------------------------------------------------------------- classifier head
__global__ __launch_bounds__(256)
void head_kernel(const unsigned short* __restrict__ probe,
                 const float* __restrict__ pooled, const bf16* __restrict__ hw,
                 const float* __restrict__ hb, void* __restrict__ out)
{
    int idx = blockIdx.x*256 + threadIdx.x;
    if (idx >= BATCH*NCLS) return;
    int b = idx & 7, n = idx >> 3;
    const float* p = pooled + b*DM;
    const unsigned short* w = (const unsigned short*)hw + (size_t)n*DM;
    float acc = hb[n];
    for (int k = 0; k < DM; k += 4) {
        ushort4 wv = *(const ushort4*)(w + k);
        acc += p[k]*us2f(wv.x) + p[k+1]*us2f(wv.y) + p[k+2]*us2f(wv.z) + p[k+3]*us2f(wv.w);
    }
    int o = b*NCLS + n;
    if (probe[0] == 0) ((float*)out)[o] = acc;
    else               ((bf16*)out)[o]  = f2b(acc);
}

// ================================================================ launcher
extern "C" void kernel_launch(void* const* d_in, const int* in_sizes, int n_in,
                              void* d_out, int out_size, void* d_ws, size_t ws_size,
                              hipStream_t stream)
{
    (void)n_in; (void)out_size;
    dim3 blk(256);

    const bool is_f32[NIN] = { false, false, true, true, true, true, false, true, true,
                               false, false, true,  true, true, true, true, false,
                               true,  true,  false, true };

    size_t off = 0;
    auto carve = [&](size_t bytes) -> void* {
        void* q = (char*)d_ws + off;
        off += (bytes + 255) & ~(size_t)255;
        return q;
    };

    CanonDesc cd;
    cd.isf32 = 0;
    cd.cum[0] = 0;
    for (int i = 0; i < NIN; ++i) {
        cd.src[i] = d_in[i];
        cd.dst[i] = carve((size_t)in_sizes[i] * (is_f32[i] ? 4 : 2));
        cd.cum[i+1] = cd.cum[i] + in_sizes[i];
        if (is_f32[i]) cd.isf32 |= (1u << i);
    }

    float* residual = (float*)carve((size_t)M_TOK*DM*4);
    bf16*  hn       = (bf16*) carve((size_t)M_TOK*DM*2);
    float* pooled   = (float*)carve((size_t)BATCH*DM*4);

    const size_t inner1 = (((size_t)SEQ*NXZ*2 + 255) & ~(size_t)255)
                          + 2*(((size_t)SEQ*DI*2 + 255) & ~(size_t)255)
                          + (((size_t)SEQ*80*2 + 255) & ~(size_t)255)
                          + (((size_t)NSEG*DI*DS*4 + 255) & ~(size_t)255)
                          + (((size_t)NSEG*DI*4 + 255) & ~(size_t)255);
    int g = 8;
    while (g > 1 && off + (size_t)g*inner1 > ws_size) g >>= 1;

    bf16*  xz     = (bf16*) carve((size_t)g*SEQ*NXZ*2);
    bf16*  xc     = (bf16*) carve((size_t)g*SEQ*DI*2);
    bf16*  ybuf   = (bf16*) carve((size_t)g*SEQ*DI*2);   // y; gate_ln in-place -> gated
    bf16*  dbc    = (bf16*) carve((size_t)g*SEQ*80*2);
    float* segb   = (float*)carve((size_t)g*NSEG*DI*DS*4);
    float* sumdtb = (float*)carve((size_t)g*NSEG*DI*4);
    bf16*  Ap     = xz;    // patch matrix, dead before first in_proj

    const unsigned short* probe = (const unsigned short*)d_in[4];  // norm_w

    canon_all<<<(cd.cum[NIN] + 255)/256, blk, 0, stream>>>(cd, probe);

    const bf16*  xin   = (const bf16*) cd.dst[0];
    const bf16*  pw    = (const bf16*) cd.dst[1];
    const float* pb    = (const float*)cd.dst[2];
    const float* chan  = (const float*)cd.dst[3];
    const float* nw    = (const float*)cd.dst[4];
    const float* nb    = (const float*)cd.dst[5];
    const bf16*  ipw   = (const bf16*) cd.dst[6];
    const float* cw    = (const float*)cd.dst[7];
    const float* cb    = (const float*)cd.dst[8];
    const bf16*  xpw   = (const bf16*) cd.dst[9];
    const bf16*  dtw   = (const bf16*) cd.dst[10];
    const float* dtbia = (const float*)cd.dst[11];
    const float* Alog  = (const float*)cd.dst[12];
    const float* Dpar  = (const float*)cd.dst[13];
    const float* snw   = (const float*)cd.dst[14];
    const float* snb   = (const float*)cd.dst[15];
    const bf16*  opw   = (const bf16*) cd.dst[16];
    const float* nfw   = (const float*)cd.dst[17];
    const float* nfb   = (const float*)cd.dst[18];
    const bf16*  hw    = (const bf16*) cd.dst[19];
    const float* hb    = (const float*)cd.dst[20];

    const int MG  = g*SEQ;
    const int GXm = (MG + 127)/128;

    for (int b0 = 0; b0 < BATCH; b0 += g) {
        gather_patches<<<MG, blk, 0, stream>>>(xin, Ap, b0);
        dim3 gr(GXm, DM/128);
        gemm_mfma<<<gr, blk, 0, stream>>>(Ap, 256, pw, 256,
                                          residual + (size_t)b0*SEQ*DM, nullptr, DM,
                                          pb, chan, MG, DM, 256, 3);
    }

    for (int l = 0; l < LAYERS; ++l) {
        ln768<<<M_TOK, blk, 0, stream>>>(residual, nw + l*DM, nb + l*DM, hn);
        for (int b0 = 0; b0 < BATCH; b0 += g) {
            const bf16* hng = hn + (size_t)b0*SEQ*DM;
            {   dim3 gr(GXm, NXZ/128);   // in_proj, single GEMM N=3072 -> xz
                gemm_mfma<<<gr, blk, 0, stream>>>(hng, DM, ipw + (size_t)l*NXZ*DM, DM,
                                                  nullptr, xz, NXZ, nullptr, nullptr,
                                                  MG, NXZ, DM, 0);
            }
            conv_silu<<<(MG*DI)/256, blk, 0, stream>>>(xz, cw + (size_t)l*DI*4, cb + l*DI, xc);
            {   dim3 gr(GXm, 1);         // x_proj (N=80)
                gemm_mfma<<<gr, blk, 0, stream>>>(xc, DI, xpw + (size_t)l*80*DI, DI,
                                                  nullptr, dbc, 80, nullptr, nullptr,
                                                  MG, 80, DI, 0);
            }
            scan_p1f<<<g*(DI/16)*NSEG, dim3(128), 0, stream>>>(xc, dbc,
                                                               dtw + (size_t)l*DI*DTR, dtbia + l*DI,
                                                               Alog + (size_t)l*DI*DS,
                                                               segb, sumdtb);
            scan_p2<<<g*(DI/16), blk, 0, stream>>>(Alog + (size_t)l*DI*DS, sumdtb, segb);
            scan_p3f<<<g*(DI/16)*NSEG, dim3(128), 0, stream>>>(xc, dbc,
                                                               dtw + (size_t)l*DI*DTR, dtbia + l*DI,
                                                               Alog + (size_t)l*DI*DS,
                                                               Dpar + l*DI, segb, ybuf);
            gate_ln<<<MG, blk, 0, stream>>>(ybuf, xz, snw + l*DI, snb + l*DI);
            {   dim3 gr(GXm, DM/128);    // out_proj += residual
                gemm_mfma<<<gr, blk, 0, stream>>>(ybuf, DI, opw + (size_t)l*DM*DI, DI,
                                                  residual + (size_t)b0*SEQ*DM, nullptr, DM,
                                                  nullptr, nullptr, MG, DM, DI, 2);
            }
        }
    }

    ln768<<<M_TOK, blk, 0, stream>>>(residual, nfw, nfb, hn);
    pool_kernel<<<(BATCH*DM)/256, blk, 0, stream>>>(hn, pooled);
    head_kernel<<<(BATCH*NCLS + 255)/256, blk, 0, stream>>>(probe, pooled, hw, hb, d_out);
}

// Round 10
// 4255.160 us; speedup vs baseline: 1.2559x; 1.2559x over previous
//
#include <hip/hip_runtime.h>
#include <hip/hip_bf16.h>

typedef __hip_bfloat16 bf16;
typedef __attribute__((ext_vector_type(8))) short short8;
typedef __attribute__((ext_vector_type(4))) float float4v;

#define BATCH 8
#define SEQ   1568            // 49 segments x 32
#define M_TOK (BATCH*SEQ)     // 12544
#define DM    768
#define DI    1536
#define NXZ   3072
#define DS    16
#define DTR   48
#define NCLS  1000
#define LAYERS 4
#define NSEG  49
#define SEGL  32
#define NIN   21

__device__ __forceinline__ float b2f(bf16 v){ return __bfloat162float(v); }
__device__ __forceinline__ bf16  f2b(float v){ return __float2bfloat16(v); }
__device__ __forceinline__ float us2f(unsigned short u){
    unsigned v = ((unsigned)u) << 16; float f; __builtin_memcpy(&f, &v, 4); return f;
}

// ---------------------------------------------------------------- fused canonicalization
struct CanonDesc {
    const void* src[NIN];
    void*       dst[NIN];
    int         cum[NIN+1];
    unsigned    isf32;
};

__global__ __launch_bounds__(256)
void canon_all(CanonDesc cd, const unsigned short* __restrict__ probe)
{
    bool f32in = (probe[0] == 0);          // norm_w[0]==1.0: fp32 low half = 0
    int i = blockIdx.x*256 + threadIdx.x;
    if (i >= cd.cum[NIN]) return;
    int lo = 0, hi = NIN;
    while (hi - lo > 1) { int mid = (lo+hi) >> 1; if (i >= cd.cum[mid]) lo = mid; else hi = mid; }
    int e = i - cd.cum[lo];
    float v = f32in ? ((const float*)cd.src[lo])[e] : b2f(((const bf16*)cd.src[lo])[e]);
    if ((cd.isf32 >> lo) & 1) ((float*)cd.dst[lo])[e] = v;
    else                      ((bf16*) cd.dst[lo])[e] = f2b(v);
}

// ---------------------------------------------------------------- gather patches
__global__ __launch_bounds__(256)
void gather_patches(const bf16* __restrict__ x, bf16* __restrict__ Ap, int b0)
{
    size_t idx = (size_t)blockIdx.x*256 + threadIdx.x;
    int i = (int)(idx & 255);
    int m = (int)(idx >> 8);
    int b = b0 + m / SEQ, s = m % SEQ;
    int hw = s >> 3, c = s & 7;
    int h = hw / 14, w = hw % 14;
    int p = i >> 4, q = i & 15;
    Ap[idx] = x[(((size_t)(b*8 + c)*224) + h*16 + p)*224 + w*16 + q];
}

// ---------------------------------------------------------------- MFMA GEMM (128x128, BK=32)
// epi 0: Cb=bf16(acc); epi 1: Cb=bf16(softplus(acc+bias[n])); epi 2: Cf+=acc;
// epi 3: Cf=acc+bias[n]+chan[(m&7)*N+n]
__global__ __launch_bounds__(256)
void gemm_mfma(const bf16* __restrict__ A, int lda,
               const bf16* __restrict__ W, int ldw,
               float* __restrict__ Cf, bf16* __restrict__ Cb, int ldc,
               const float* __restrict__ bias, const float* __restrict__ chan,
               int M, int N, int K, int epi)
{
    __shared__ short As[128*40];
    __shared__ short Bs[128*40];
    int tid  = threadIdx.x;
    int m0   = blockIdx.x*128, n0 = blockIdx.y*128;
    int lane = tid & 63, wv = tid >> 6;
    int wm = (wv >> 1)*64, wn = (wv & 1)*64;
    int l15 = lane & 15, quad = lane >> 4;

    float4v acc[4][4];
    #pragma unroll
    for (int i = 0; i < 4; ++i)
        #pragma unroll
        for (int j = 0; j < 4; ++j) acc[i][j] = (float4v){0.f,0.f,0.f,0.f};

    const short8 zv8 = {0,0,0,0,0,0,0,0};
    for (int k0 = 0; k0 < K; k0 += 32) {
        #pragma unroll
        for (int u = 0; u < 2; ++u) {
            int c   = tid*2 + u;
            int row = c >> 2, ch = c & 3;
            bool kok = (k0 + ch*8 + 8) <= K;
            short8 va = (kok && m0 + row < M)
                ? *(const short8*)((const short*)A + (size_t)(m0+row)*lda + k0 + ch*8) : zv8;
            *(short8*)(As + row*40 + ch*8) = va;
            short8 vb = (kok && n0 + row < N)
                ? *(const short8*)((const short*)W + (size_t)(n0+row)*ldw + k0 + ch*8) : zv8;
            *(short8*)(Bs + row*40 + ch*8) = vb;
        }
        __syncthreads();
        short8 av[4], bv[4];
        #pragma unroll
        for (int i = 0; i < 4; ++i) av[i] = *(const short8*)(As + (wm + i*16 + l15)*40 + quad*8);
        #pragma unroll
        for (int j = 0; j < 4; ++j) bv[j] = *(const short8*)(Bs + (wn + j*16 + l15)*40 + quad*8);
        #pragma unroll
        for (int i = 0; i < 4; ++i)
            #pragma unroll
            for (int j = 0; j < 4; ++j)
                acc[i][j] = __builtin_amdgcn_mfma_f32_16x16x32_bf16(av[i], bv[j], acc[i][j], 0, 0, 0);
        __syncthreads();
    }

    #pragma unroll
    for (int i = 0; i < 4; ++i) {
        #pragma unroll
        for (int j = 0; j < 4; ++j) {
            int gn = n0 + wn + j*16 + l15;
            if (gn >= N) continue;
            #pragma unroll
            for (int r = 0; r < 4; ++r) {
                int gm = m0 + wm + i*16 + quad*4 + r;
                if (gm >= M) continue;
                float v = acc[i][j][r];
                size_t off = (size_t)gm*ldc + gn;
                if (epi == 0)      Cb[off] = f2b(v);
                else if (epi == 1) {
                    v += bias[gn];
                    v = (v > 20.f) ? v : log1pf(__expf(v));
                    Cb[off] = f2b(v);
                }
                else if (epi == 2) Cf[off] += v;
                else               Cf[off] = v + bias[gn] + chan[(size_t)(gm & 7)*N + gn];
            }
        }
    }
}

// ---------------------------------------------------------------- LayerNorm 768
__global__ __launch_bounds__(256)
void ln768(const float* __restrict__ X, const float* __restrict__ w,
           const float* __restrict__ bb, bf16* __restrict__ out)
{
    __shared__ float red[8];
    size_t t = blockIdx.x;
    const float* x = X + t*DM;
    float v[3]; float s = 0.f, s2 = 0.f;
    #pragma unroll
    for (int r = 0; r < 3; ++r) {
        v[r] = x[threadIdx.x + 256*r];
        s += v[r]; s2 += v[r]*v[r];
    }
    #pragma unroll
    for (int o = 32; o; o >>= 1) { s += __shfl_down(s, o, 64); s2 += __shfl_down(s2, o, 64); }
    if ((threadIdx.x & 63) == 0) { red[threadIdx.x >> 6] = s; red[(threadIdx.x >> 6) + 4] = s2; }
    __syncthreads();
    s  = red[0]+red[1]+red[2]+red[3];
    s2 = red[4]+red[5]+red[6]+red[7];
    float mu  = s * (1.f/DM);
    float inv = rsqrtf(fmaxf(s2*(1.f/DM) - mu*mu, 0.f) + 1e-5f);
    #pragma unroll
    for (int r = 0; r < 3; ++r) {
        int i = threadIdx.x + 256*r;
        out[t*DM + i] = f2b((v[r]-mu)*inv*w[i] + bb[i]);
    }
}

// ---------------------------------------------------------------- causal depthwise conv (k=4) + silu
// reads x-half of xz (stride NXZ), writes xc (stride DI)
__global__ __launch_bounds__(256)
void conv_silu(const bf16* __restrict__ xz, const float* __restrict__ cw,
               const float* __restrict__ cb, bf16* __restrict__ xc)
{
    size_t idx = (size_t)blockIdx.x*256 + threadIdx.x;
    int d = (int)(idx % DI);
    int m = (int)(idx / DI);
    int b = m / SEQ, t = m % SEQ;
    float acc = cb[d];
    #pragma unroll
    for (int k = 0; k < 4; ++k) {
        int tt = t + k - 3;
        if (tt >= 0)
            acc += b2f(xz[(size_t)(b*SEQ + tt)*NXZ + d]) * cw[d*4 + k];
    }
    float sig = 1.f/(1.f + __expf(-acc));
    xc[idx] = f2b(acc*sig);
}

// ================================================================ chunked selective scan (round-8 proven)
// ---- pass 1: per-segment summaries (B_seg, sum_dt). 1 wave per (b,dblk,si). ----
__global__ __launch_bounds__(64)
void scan_p1(const bf16* __restrict__ dt, const bf16* __restrict__ x,
             const bf16* __restrict__ dbc, const float* __restrict__ Alog,
             float* __restrict__ seg, float* __restrict__ sumdt)
{
    __shared__ float dtT[16][36], xT[16][36];   // [dl][t]
    __shared__ float Bsh[32][20];               // [t][n]
    int si = blockIdx.x % NSEG;
    int tt = blockIdx.x / NSEG;
    int dblk = tt % (DI/16);
    int b = tt / (DI/16);
    int d0 = dblk*16;
    int tid = threadIdx.x;
    int s = tid & 3, dl = tid >> 2, d = d0 + dl;

    float4v Av = *(const float4v*)&Alog[(size_t)d*DS + s*4];
    float A2[4], S[4];
    #pragma unroll
    for (int k = 0; k < 4; ++k) { A2[k] = -__expf(Av[k]) * 1.44269504f; S[k] = 0.f; }

    int r = tid & 31, p = tid >> 5;
    size_t rowm = (size_t)(b*SEQ + si*SEGL + r);
    short8 vdt = *(const short8*)((const unsigned short*)dt  + rowm*DI + d0 + p*8);
    short8 vx  = *(const short8*)((const unsigned short*)x   + rowm*DI + d0 + p*8);
    short8 vB  = *(const short8*)((const unsigned short*)dbc + rowm*80 + DTR + p*8);
    #pragma unroll
    for (int i = 0; i < 8; ++i) {
        dtT[p*8+i][r] = us2f((unsigned short)vdt[i]);
        xT [p*8+i][r] = us2f((unsigned short)vx[i]);
        Bsh[r][p*8+i] = us2f((unsigned short)vB[i]);
    }
    __syncthreads();

    float sdt = 0.f;
    #pragma unroll
    for (int t4 = 0; t4 < 8; ++t4) {
        float4v dv  = *(const float4v*)&dtT[dl][t4*4];
        float4v xv4 = *(const float4v*)&xT [dl][t4*4];
        #pragma unroll
        for (int jq = 0; jq < 4; ++jq) {
            int j = t4*4 + jq;
            float dtv = dv[jq], xv = xv4[jq];
            float dtx = dtv*xv;
            sdt += dtv;
            float4v Bv = *(const float4v*)&Bsh[j][s*4];
            #pragma unroll
            for (int k = 0; k < 4; ++k)
                S[k] = exp2f(dtv*A2[k])*S[k] + dtx*Bv[k];
        }
    }
    size_t o = ((size_t)(b*NSEG + si)*DI + d)*DS + s*4;
    *(float4v*)&seg[o] = (float4v){S[0], S[1], S[2], S[3]};
    if (s == 0) sumdt[(size_t)(b*NSEG + si)*DI + d] = sdt;
}

// ---- pass 2: 49-step boundary scan, in-place ----
__global__ __launch_bounds__(256)
void scan_p2(const float* __restrict__ Alog, const float* __restrict__ sumdt,
             float* seg)
{
    int dblk = blockIdx.x % (DI/16), b = blockIdx.x / (DI/16);
    int n = threadIdx.x & 15, dl = threadIdx.x >> 4;
    int d = dblk*16 + dl;
    float A2 = -__expf(Alog[(size_t)d*DS + n]) * 1.44269504f;
    float h = 0.f;
    for (int si = 0; si < NSEG; ++si) {
        float sdt = sumdt[(size_t)(b*NSEG + si)*DI + d];
        size_t o = ((size_t)(b*NSEG + si)*DI + d)*DS + n;
        float Bv = seg[o];
        seg[o] = h;
        h = exp2f(A2*sdt)*h + Bv;
    }
}

// ---- pass 3: within-segment scan from h_pre, emit y ----
__global__ __launch_bounds__(64)
void scan_p3(const bf16* __restrict__ dt, const bf16* __restrict__ x,
             const bf16* __restrict__ dbc, const float* __restrict__ Alog,
             const float* __restrict__ Dpar, const float* __restrict__ seg,
             bf16* __restrict__ y)
{
    __shared__ float dtT[16][36], xT[16][36];
    __shared__ float Bsh[32][20], Csh[32][20];
    __shared__ bf16  ys[32][16];
    int si = blockIdx.x % NSEG;
    int tt = blockIdx.x / NSEG;
    int dblk = tt % (DI/16);
    int b = tt / (DI/16);
    int d0 = dblk*16;
    int tid = threadIdx.x;
    int s = tid & 3, dl = tid >> 2, d = d0 + dl;

    float4v Av = *(const float4v*)&Alog[(size_t)d*DS + s*4];
    float A2[4], h[4];
    float4v hv = *(const float4v*)&seg[((size_t)(b*NSEG + si)*DI + d)*DS + s*4];
    #pragma unroll
    for (int k = 0; k < 4; ++k) { A2[k] = -__expf(Av[k]) * 1.44269504f; h[k] = hv[k]; }
    float Dv = Dpar[d];

    int r = tid & 31, p = tid >> 5;
    size_t rowm = (size_t)(b*SEQ + si*SEGL + r);
    short8 vdt = *(const short8*)((const unsigned short*)dt  + rowm*DI + d0 + p*8);
    short8 vx  = *(const short8*)((const unsigned short*)x   + rowm*DI + d0 + p*8);
    short8 vB  = *(const short8*)((const unsigned short*)dbc + rowm*80 + DTR + p*8);
    short8 vC  = *(const short8*)((const unsigned short*)dbc + rowm*80 + DTR + DS + p*8);
    #pragma unroll
    for (int i = 0; i < 8; ++i) {
        dtT[p*8+i][r] = us2f((unsigned short)vdt[i]);
        xT [p*8+i][r] = us2f((unsigned short)vx[i]);
        Bsh[r][p*8+i] = us2f((unsigned short)vB[i]);
        Csh[r][p*8+i] = us2f((unsigned short)vC[i]);
    }
    __syncthreads();

    #pragma unroll
    for (int half = 0; half < 2; ++half) {
        float pr[16];
        #pragma unroll
        for (int t4 = 0; t4 < 4; ++t4) {
            float4v dv  = *(const float4v*)&dtT[dl][half*16 + t4*4];
            float4v xv4 = *(const float4v*)&xT [dl][half*16 + t4*4];
            #pragma unroll
            for (int jq = 0; jq < 4; ++jq) {
                int j = t4*4 + jq;
                int tgl = half*16 + j;
                float dtv = dv[jq], xv = xv4[jq];
                float dtx = dtv*xv;
                float4v Bv = *(const float4v*)&Bsh[tgl][s*4];
                float4v Cv = *(const float4v*)&Csh[tgl][s*4];
                float pp = 0.f;
                #pragma unroll
                for (int k = 0; k < 4; ++k) {
                    h[k] = exp2f(dtv*A2[k])*h[k] + dtx*Bv[k];
                    pp += h[k]*Cv[k];
                }
                if (s == 0) pp += Dv*xv;
                pr[j] = pp;
            }
        }
        #pragma unroll
        for (int j = 0; j < 16; ++j) {
            float pp = pr[j];
            pp += __shfl_xor(pp, 1, 4);
            pp += __shfl_xor(pp, 2, 4);
            if (s == 0) ys[half*16 + j][dl] = f2b(pp);
        }
    }
    __syncthreads();
    short8 vy = *(const short8*)((const unsigned short*)&ys[r][0] + p*8);
    *(short8*)((unsigned short*)y + rowm*DI + d0 + p*8) = vy;
}

// ---------------------------------------------------------------- LN(1536)*silu(z); in-place over y
__global__ __launch_bounds__(256)
void gate_ln(bf16* y, const bf16* __restrict__ xz,
             const float* __restrict__ w, const float* __restrict__ bb)
{
    __shared__ float red[8];
    size_t t = blockIdx.x;
    bf16* yy = y + t*DI;
    const bf16* zz = xz + t*NXZ + DI;
    float v[6]; float s = 0.f, s2 = 0.f;
    #pragma unroll
    for (int r = 0; r < 6; ++r) {
        v[r] = b2f(yy[threadIdx.x + 256*r]);
        s += v[r]; s2 += v[r]*v[r];
    }
    #pragma unroll
    for (int o = 32; o; o >>= 1) { s += __shfl_down(s, o, 64); s2 += __shfl_down(s2, o, 64); }
    if ((threadIdx.x & 63) == 0) { red[threadIdx.x >> 6] = s; red[(threadIdx.x >> 6) + 4] = s2; }
    __syncthreads();
    s  = red[0]+red[1]+red[2]+red[3];
    s2 = red[4]+red[5]+red[6]+red[7];
    float mu  = s * (1.f/DI);
    float inv = rsqrtf(fmaxf(s2*(1.f/DI) - mu*mu, 0.f) + 1e-5f);
    #pragma unroll
    for (int r = 0; r < 6; ++r) {
        int i = threadIdx.x + 256*r;
        float zv = b2f(zz[i]);
        float sig = 1.f/(1.f + __expf(-zv));
        yy[i] = f2b(((v[r]-mu)*inv*w[i] + bb[i]) * (zv*sig));
    }
}

// ---------------------------------------------------------------- mean pool over tokens
__global__ __launch_bounds__(256)
void pool_kernel(const bf16* __restrict__ hf, float* __restrict__ pooled)
{
    int idx = blockIdx.x*256 + threadIdx.x;
    int b = idx / DM, dm = idx % DM;
    const bf16* p = hf + (size_t)b*SEQ*DM + dm;
    float s = 0.f;
    for (int t = 0; t < SEQ; ++t) s += b2f(p[(size_t)t*DM]);
    pooled[idx] = s * (1.f/SEQ);
}

// ---------------------------------------------------------------- classifier head
__global__ __launch_bounds__(256)
void head_kernel(const unsigned short* __restrict__ probe,
                 const float* __restrict__ pooled, const bf16* __restrict__ hw,
                 const float* __restrict__ hb, void* __restrict__ out)
{
    int idx = blockIdx.x*256 + threadIdx.x;
    if (idx >= BATCH*NCLS) return;
    int b = idx & 7, n = idx >> 3;
    const float* p = pooled + b*DM;
    const unsigned short* w = (const unsigned short*)hw + (size_t)n*DM;
    float acc = hb[n];
    for (int k = 0; k < DM; k += 4) {
        ushort4 wv = *(const ushort4*)(w + k);
        acc += p[k]*us2f(wv.x) + p[k+1]*us2f(wv.y) + p[k+2]*us2f(wv.z) + p[k+3]*us2f(wv.w);
    }
    int o = b*NCLS + n;
    if (probe[0] == 0) ((float*)out)[o] = acc;
    else               ((bf16*)out)[o]  = f2b(acc);
}

// ================================================================ launcher
extern "C" void kernel_launch(void* const* d_in, const int* in_sizes, int n_in,
                              void* d_out, int out_size, void* d_ws, size_t ws_size,
                              hipStream_t stream)
{
    (void)n_in; (void)out_size;
    dim3 blk(256);

    const bool is_f32[NIN] = { false, false, true, true, true, true, false, true, true,
                               false, false, true,  true, true, true, true, false,
                               true,  true,  false, true };

    size_t off = 0;
    auto carve = [&](size_t bytes) -> void* {
        void* q = (char*)d_ws + off;
        off += (bytes + 255) & ~(size_t)255;
        return q;
    };

    CanonDesc cd;
    cd.isf32 = 0;
    cd.cum[0] = 0;
    for (int i = 0; i < NIN; ++i) {
        cd.src[i] = d_in[i];
        cd.dst[i] = carve((size_t)in_sizes[i] * (is_f32[i] ? 4 : 2));
        cd.cum[i+1] = cd.cum[i] + in_sizes[i];
        if (is_f32[i]) cd.isf32 |= (1u << i);
    }

    float* residual = (float*)carve((size_t)M_TOK*DM*4);
    bf16*  hn       = (bf16*) carve((size_t)M_TOK*DM*2);
    float* pooled   = (float*)carve((size_t)BATCH*DM*4);

    const size_t inner1 = (((size_t)SEQ*NXZ*2 + 255) & ~(size_t)255)
                          + 3*(((size_t)SEQ*DI*2 + 255) & ~(size_t)255)
                          + (((size_t)SEQ*80*2 + 255) & ~(size_t)255)
                          + (((size_t)NSEG*DI*DS*4 + 255) & ~(size_t)255)
                          + (((size_t)NSEG*DI*4 + 255) & ~(size_t)255);
    int g = 8;
    while (g > 1 && off + (size_t)g*inner1 > ws_size) g >>= 1;

    bf16*  xz     = (bf16*) carve((size_t)g*SEQ*NXZ*2);
    bf16*  xc     = (bf16*) carve((size_t)g*SEQ*DI*2);
    bf16*  ybuf   = (bf16*) carve((size_t)g*SEQ*DI*2);   // y; gate_ln in-place -> gated
    bf16*  dtb    = (bf16*) carve((size_t)g*SEQ*DI*2);
    bf16*  dbc    = (bf16*) carve((size_t)g*SEQ*80*2);
    float* segb   = (float*)carve((size_t)g*NSEG*DI*DS*4);
    float* sumdtb = (float*)carve((size_t)g*NSEG*DI*4);
    bf16*  Ap     = xz;    // patch matrix, dead before first in_proj

    const unsigned short* probe = (const unsigned short*)d_in[4];  // norm_w

    canon_all<<<(cd.cum[NIN] + 255)/256, blk, 0, stream>>>(cd, probe);

    const bf16*  xin   = (const bf16*) cd.dst[0];
    const bf16*  pw    = (const bf16*) cd.dst[1];
    const float* pb    = (const float*)cd.dst[2];
    const float* chan  = (const float*)cd.dst[3];
    const float* nw    = (const float*)cd.dst[4];
    const float* nb    = (const float*)cd.dst[5];
    const bf16*  ipw   = (const bf16*) cd.dst[6];
    const float* cw    = (const float*)cd.dst[7];
    const float* cb    = (const float*)cd.dst[8];
    const bf16*  xpw   = (const bf16*) cd.dst[9];
    const bf16*  dtw   = (const bf16*) cd.dst[10];
    const float* dtbia = (const float*)cd.dst[11];
    const float* Alog  = (const float*)cd.dst[12];
    const float* Dpar  = (const float*)cd.dst[13];
    const float* snw   = (const float*)cd.dst[14];
    const float* snb   = (const float*)cd.dst[15];
    const bf16*  opw   = (const bf16*) cd.dst[16];
    const float* nfw   = (const float*)cd.dst[17];
    const float* nfb   = (const float*)cd.dst[18];
    const bf16*  hw    = (const bf16*) cd.dst[19];
    const float* hb    = (const float*)cd.dst[20];

    const int MG  = g*SEQ;
    const int GXm = (MG + 127)/128;

    for (int b0 = 0; b0 < BATCH; b0 += g) {
        gather_patches<<<MG, blk, 0, stream>>>(xin, Ap, b0);
        dim3 gr(GXm, DM/128);
        gemm_mfma<<<gr, blk, 0, stream>>>(Ap, 256, pw, 256,
                                          residual + (size_t)b0*SEQ*DM, nullptr, DM,
                                          pb, chan, MG, DM, 256, 3);
    }

    for (int l = 0; l < LAYERS; ++l) {
        ln768<<<M_TOK, blk, 0, stream>>>(residual, nw + l*DM, nb + l*DM, hn);
        for (int b0 = 0; b0 < BATCH; b0 += g) {
            const bf16* hng = hn + (size_t)b0*SEQ*DM;
            {   dim3 gr(GXm, NXZ/128);   // in_proj, single GEMM N=3072 -> xz
                gemm_mfma<<<gr, blk, 0, stream>>>(hng, DM, ipw + (size_t)l*NXZ*DM, DM,
                                                  nullptr, xz, NXZ, nullptr, nullptr,
                                                  MG, NXZ, DM, 0);
            }
            conv_silu<<<(MG*DI)/256, blk, 0, stream>>>(xz, cw + (size_t)l*DI*4, cb + l*DI, xc);
            {   dim3 gr(GXm, 1);         // x_proj (N=80)
                gemm_mfma<<<gr, blk, 0, stream>>>(xc, DI, xpw + (size_t)l*80*DI, DI,
                                                  nullptr, dbc, 80, nullptr, nullptr,
                                                  MG, 80, DI, 0);
            }
            {   dim3 gr(GXm, DI/128);    // dt_proj + softplus (K=48 zero-padded)
                gemm_mfma<<<gr, blk, 0, stream>>>(dbc, 80, dtw + (size_t)l*DI*DTR, DTR,
                                                  nullptr, dtb, DI, dtbia + l*DI, nullptr,
                                                  MG, DI, DTR, 1);
            }
            scan_p1<<<g*(DI/16)*NSEG, dim3(64), 0, stream>>>(dtb, xc, dbc,
                                                             Alog + (size_t)l*DI*DS,
                                                             segb, sumdtb);
            scan_p2<<<g*(DI/16), blk, 0, stream>>>(Alog + (size_t)l*DI*DS, sumdtb, segb);
            scan_p3<<<g*(DI/16)*NSEG, dim3(64), 0, stream>>>(dtb, xc, dbc,
                                                             Alog + (size_t)l*DI*DS,
                                                             Dpar + l*DI, segb, ybuf);
            gate_ln<<<MG, blk, 0, stream>>>(ybuf, xz, snw + l*DI, snb + l*DI);
            {   dim3 gr(GXm, DM/128);    // out_proj += residual
                gemm_mfma<<<gr, blk, 0, stream>>>(ybuf, DI, opw + (size_t)l*DM*DI, DI,
                                                  residual + (size_t)b0*SEQ*DM, nullptr, DM,
                                                  nullptr, nullptr, MG, DM, DI, 2);
            }
        }
    }

    ln768<<<M_TOK, blk, 0, stream>>>(residual, nfw, nfb, hn);
    pool_kernel<<<(BATCH*DM)/256, blk, 0, stream>>>(hn, pooled);
    head_kernel<<<(BATCH*NCLS + 255)/256, blk, 0, stream>>>(probe, pooled, hw, hb, d_out);
}